// Round 3
// baseline (305.616 us; speedup 1.0000x reference)
//
#include <hip/hip_runtime.h>

#define D_ 512
#define L_ 256
#define B_ 16
#define T_ 3072
#define MELS_ 80
#define R_ 4096          // B_*L_ unique token rows
#define CS_ 4104         // mel^T column stride (floats)
#define NBLK 512

typedef __bf16 bf16x8 __attribute__((ext_vector_type(8)));
typedef float f32x4 __attribute__((ext_vector_type(4)));

__device__ __forceinline__ unsigned f2bf(float f) {
  union { float f; unsigned u; } x; x.f = f;
  return (x.u + 0x7FFFu + ((x.u >> 16) & 1u)) >> 16;   // RNE
}

// ---- device-scope grid barrier (counters pre-zeroed by hipMemsetAsync) ----
__device__ __forceinline__ void gbar(int* bar, int id) {
  __syncthreads();
  if (threadIdx.x == 0) {
    __threadfence();                                   // agent release: wbl2
    atomicAdd(&bar[id], 1);
    while (__hip_atomic_load(&bar[id], __ATOMIC_RELAXED, __HIP_MEMORY_SCOPE_AGENT) < NBLK)
      __builtin_amdgcn_s_sleep(2);
    __threadfence();                                   // agent acquire: inv
  }
  __syncthreads();
}

// dst[n][k] = bf16(src[k][n]) ; src is [512][N] f32, dst is [N][512] bf16
__device__ __forceinline__ void transw_dev(const float* __restrict__ src,
                                           unsigned short* __restrict__ dst,
                                           int N, int local, float* sh) {
  int kt = local & 7, nt = local >> 3;
  int k0 = kt * 64, n0 = nt * 64;
  int tid = threadIdx.x;
  int c = tid & 63, r4 = tid >> 6;
  for (int it = 0; it < 16; ++it) {
    int r = it * 4 + r4;
    int n = n0 + c;
    sh[r * 65 + c] = (n < N) ? src[(k0 + r) * N + n] : 0.f;
  }
  __syncthreads();
  for (int it = 0; it < 16; ++it) {
    int r = it * 4 + r4;
    int n = n0 + r;
    if (n < N) dst[n * D_ + k0 + c] = (unsigned short)f2bf(sh[c * 65 + r]);
  }
}

// cumsum(dur) + searchsorted(right) -> enc-row index per frame (R_ = invalid)
__device__ __forceinline__ void tok_dev(const int* __restrict__ dur,
                                        int* __restrict__ TOK, int b, int* cs) {
  int tid = threadIdx.x;
  cs[tid] = dur[b * L_ + tid];
  for (int off = 1; off < L_; off <<= 1) {
    __syncthreads();
    int v = (tid >= off) ? cs[tid - off] : 0;
    __syncthreads();
    cs[tid] += v;
  }
  __syncthreads();
  for (int t = tid; t < T_; t += 256) {
    int lo = 0, hi = L_;
    while (lo < hi) { int mid = (lo + hi) >> 1; if (cs[mid] <= t) lo = mid + 1; else hi = mid; }
    TOK[b * T_ + t] = (lo < L_) ? (b * L_ + lo) : R_;
  }
}

// ---- C = relu(A @ Bt^T + bias); 64x64 tile, BK=64, global_load_lds w=16 ----
// If wdur != null, also accumulate durout[m] += sum_n C[m][n]*wdur[n] (atomic).
__device__ __forceinline__ void gemm_tile(
    const unsigned short* __restrict__ A, const unsigned short* __restrict__ Bt,
    const float* __restrict__ bias, unsigned short* __restrict__ C,
    int m0, int n0, short* lsA, short* lsB,
    const float* __restrict__ wdur, float* __restrict__ durout) {
  int tid = threadIdx.x;
  int lane = tid & 63, w = tid >> 6;
  int wm = w >> 1, wn = w & 1;
  int col = lane & 15, quad = lane >> 4;
  f32x4 acc[2][2] = {};
  for (int ks = 0; ks < 8; ++ks) {
    int k0 = ks * 64;
    __syncthreads();                                  // protect LDS reuse
    for (int it = 0; it < 2; ++it) {
      int linear = it * 256 + tid;
      int row = linear >> 3, p = linear & 7;
      int seg = (p + row) & 7;                        // additive swizzle
      const unsigned short* ga = A + (size_t)(m0 + row) * D_ + k0 + seg * 8;
      const unsigned short* gb = Bt + (size_t)(n0 + row) * D_ + k0 + seg * 8;
      short* la = lsA + (size_t)(it * 256 + (tid & ~63)) * 8;  // wave-uniform base
      short* lb = lsB + (size_t)(it * 256 + (tid & ~63)) * 8;
      __builtin_amdgcn_global_load_lds((const __attribute__((address_space(1))) void*)ga,
                                       (__attribute__((address_space(3))) void*)la, 16, 0, 0);
      __builtin_amdgcn_global_load_lds((const __attribute__((address_space(1))) void*)gb,
                                       (__attribute__((address_space(3))) void*)lb, 16, 0, 0);
    }
    __syncthreads();                                  // drains vmcnt(0)
    for (int kk = 0; kk < 2; ++kk) {
      int s = kk * 4 + quad;
      bf16x8 af[2], bfr[2];
      for (int mt = 0; mt < 2; ++mt) {
        int r = wm * 32 + mt * 16 + col;
        int p = (s - r) & 7;
        af[mt] = *(const bf16x8*)(lsA + ((size_t)r * 8 + p) * 8);
      }
      for (int nt = 0; nt < 2; ++nt) {
        int r = wn * 32 + nt * 16 + col;
        int p = (s - r) & 7;
        bfr[nt] = *(const bf16x8*)(lsB + ((size_t)r * 8 + p) * 8);
      }
      for (int mt = 0; mt < 2; ++mt)
        for (int nt = 0; nt < 2; ++nt)
          acc[mt][nt] = __builtin_amdgcn_mfma_f32_16x16x32_bf16(af[mt], bfr[nt], acc[mt][nt], 0, 0, 0);
    }
  }
  float dpart[2][4] = {{0.f,0.f,0.f,0.f},{0.f,0.f,0.f,0.f}};
  for (int nt = 0; nt < 2; ++nt) {
    int n = n0 + wn * 32 + nt * 16 + col;
    float bn = bias[n];
    float wdn = wdur ? wdur[n] : 0.f;
    for (int mt = 0; mt < 2; ++mt) {
      int mb = m0 + wm * 32 + mt * 16 + quad * 4;
      for (int i = 0; i < 4; ++i) {
        float v = acc[mt][nt][i] + bn;
        v = v > 0.f ? v : 0.f;
        C[(size_t)(mb + i) * D_ + n] = (unsigned short)f2bf(v);
        dpart[mt][i] += v * wdn;
      }
    }
  }
  if (wdur) {
    for (int off = 1; off < 16; off <<= 1)
      for (int mt = 0; mt < 2; ++mt)
        for (int i = 0; i < 4; ++i)
          dpart[mt][i] += __shfl_xor(dpart[mt][i], off, 64);
    if (col == 0)
      for (int mt = 0; mt < 2; ++mt)
        for (int i = 0; i < 4; ++i)
          atomicAdd(&durout[m0 + wm * 32 + mt * 16 + quad * 4 + i], dpart[mt][i]);
  }
}

__global__ __launch_bounds__(256, 2) void fused_all(
    const int* __restrict__ src, const int* __restrict__ dur,
    const float* __restrict__ emb, const float* __restrict__ pos,
    const float* __restrict__ Wenc, const float* __restrict__ benc,
    const float* __restrict__ Wdur, const float* __restrict__ bdur,
    const float* __restrict__ Wdec, const float* __restrict__ bdec,
    const float* __restrict__ Wgen, const float* __restrict__ bgen,
    unsigned short* __restrict__ X, unsigned short* __restrict__ ENC,
    unsigned short* __restrict__ DEC, unsigned short* __restrict__ WET,
    unsigned short* __restrict__ WDT, unsigned short* __restrict__ WGT,
    int* __restrict__ TOK, float* __restrict__ MELT, int* __restrict__ bar,
    float* __restrict__ out, float* __restrict__ durout) {
  __shared__ __align__(16) char smem[20480];
  short* lsA = (short*)smem;
  short* lsB = (short*)(smem + 8192);
  int bid = blockIdx.x, tid = threadIdx.x;
  int lane = tid & 63;

  // ---------------- P0: prep ----------------
  for (int u = 0; u < 2; ++u) {                       // X = bf16(emb[src]+pos), 8 rows/blk
    int row = bid * 8 + u * 4 + (tid >> 6);
    int s = src[row];
    int l = row & (L_ - 1);
    int d = lane * 8;
    const float4* ep = (const float4*)(emb + (size_t)s * D_ + d);
    const float4* pp = (const float4*)(pos + (size_t)l * D_ + d);
    float4 a0 = ep[0], a1 = ep[1];
    float4 b0 = pp[0], b1 = pp[1];
    uint4 o;
    o.x = f2bf(a0.x + b0.x) | (f2bf(a0.y + b0.y) << 16);
    o.y = f2bf(a0.z + b0.z) | (f2bf(a0.w + b0.w) << 16);
    o.z = f2bf(a1.x + b1.x) | (f2bf(a1.y + b1.y) << 16);
    o.w = f2bf(a1.z + b1.z) | (f2bf(a1.w + b1.w) << 16);
    *(uint4*)(X + (size_t)row * D_ + d) = o;
  }
  if (bid < 64)       transw_dev(Wenc, WET, 512, bid, (float*)smem);
  else if (bid < 128) transw_dev(Wdec, WDT, 512, bid - 64, (float*)smem);
  else if (bid < 144) transw_dev(Wgen, WGT, MELS_, bid - 128, (float*)smem);
  else if (bid < 160) tok_dev(dur, TOK, bid - 144, (int*)smem);
  else if (bid == 160) {                              // DEC[R_] = relu(b_dec)
    if (tid < 64) {
      int d = lane * 8;
      float4 c0 = *(const float4*)(bdec + d);
      float4 c1 = *(const float4*)(bdec + d + 4);
      uint4 o;
      o.x = f2bf(fmaxf(c0.x, 0.f)) | (f2bf(fmaxf(c0.y, 0.f)) << 16);
      o.y = f2bf(fmaxf(c0.z, 0.f)) | (f2bf(fmaxf(c0.w, 0.f)) << 16);
      o.z = f2bf(fmaxf(c1.x, 0.f)) | (f2bf(fmaxf(c1.y, 0.f)) << 16);
      o.w = f2bf(fmaxf(c1.z, 0.f)) | (f2bf(fmaxf(c1.w, 0.f)) << 16);
      *(uint4*)(DEC + (size_t)R_ * D_ + d) = o;
    }
  } else if (bid == 161) {                            // durout = b_dur (atomic base)
    float bv = bdur[0];
    for (int i = tid; i < R_; i += 256) durout[i] = bv;
  }
  gbar(bar, 0);

  // ---------------- P1: encoder GEMM + duration head ----------------
  gemm_tile(X, WET, benc, ENC, (bid >> 3) * 64, (bid & 7) * 64, lsA, lsB, Wdur, durout);
  gbar(bar, 1);

  // ---------------- P2: decoder GEMM ----------------
  gemm_tile(ENC, WDT, bdec, DEC, (bid >> 3) * 64, (bid & 7) * 64, lsA, lsB, nullptr, nullptr);
  gbar(bar, 2);

  // ---------------- P3: generator -> mel^T [80 x 4097] ----------------
  if (bid < 257) {
    float* shg = (float*)smem;                        // 4*80*16 partials
    int w = tid >> 6;
    int col = lane & 15, quad = lane >> 4;
    int n0 = bid * 16;
    int n = n0 + col;
    int nc = min(n, R_);
    f32x4 acc[5] = {};
    const unsigned short* dp = DEC + (size_t)nc * D_ + quad * 8;
    for (int ks = 0; ks < 4; ++ks) {
      int k0 = (w * 4 + ks) * 32;
      bf16x8 bfr = *(const bf16x8*)(dp + k0);
      for (int mt = 0; mt < 5; ++mt) {
        bf16x8 afr = *(const bf16x8*)(WGT + (size_t)(mt * 16 + col) * D_ + k0 + quad * 8);
        acc[mt] = __builtin_amdgcn_mfma_f32_16x16x32_bf16(afr, bfr, acc[mt], 0, 0, 0);
      }
    }
    for (int mt = 0; mt < 5; ++mt)
      for (int i = 0; i < 4; ++i)
        shg[w * 1280 + (mt * 16 + quad * 4 + i) * 16 + col] = acc[mt][i];
    __syncthreads();
    for (int j = 0; j < 5; ++j) {
      int idx = j * 256 + tid;
      float v = shg[idx] + shg[1280 + idx] + shg[2560 + idx] + shg[3840 + idx];
      int m = idx >> 4;
      int nn = n0 + (idx & 15);
      if (nn <= R_) MELT[(size_t)m * CS_ + nn] = v + bgen[m];
    }
  }
  gbar(bar, 3);

  // ---------------- P4: gather + transpose scatter ----------------
  if (bid < 384) {
    int b = bid / 24;
    int tl = (bid % 24) * 128 + (tid & 31) * 4;
    int m0 = tid >> 5;
    int4 tg = *(const int4*)(TOK + b * T_ + tl);
    float* ob = out + (size_t)b * MELS_ * T_ + tl;
    for (int it = 0; it < 10; ++it) {
      int m = m0 + it * 8;
      const float* mr = MELT + (size_t)m * CS_;
      float4 v = make_float4(mr[tg.x], mr[tg.y], mr[tg.z], mr[tg.w]);
      *(float4*)(ob + (size_t)m * T_) = v;
    }
  }
}

extern "C" void kernel_launch(void* const* d_in, const int* in_sizes, int n_in,
                              void* d_out, int out_size, void* d_ws, size_t ws_size,
                              hipStream_t stream) {
  const int* src = (const int*)d_in[0];
  const int* dur = (const int*)d_in[1];
  const float* emb = (const float*)d_in[3];
  const float* pos = (const float*)d_in[4];
  const float* Wenc = (const float*)d_in[5];
  const float* benc = (const float*)d_in[6];
  const float* Wdur = (const float*)d_in[7];
  const float* bdur = (const float*)d_in[8];
  const float* Wdec = (const float*)d_in[9];
  const float* bdec = (const float*)d_in[10];
  const float* Wgen = (const float*)d_in[11];
  const float* bgen = (const float*)d_in[12];

  char* ws = (char*)d_ws;
  unsigned short* X   = (unsigned short*)(ws + 0);          // 4096x512 bf16
  unsigned short* ENC = (unsigned short*)(ws + 4194304);    // 4096x512 bf16
  unsigned short* DEC = (unsigned short*)(ws + 8388608);    // 4097x512 bf16 (row 4096 = relu(b_dec))
  unsigned short* WET = (unsigned short*)(ws + 12583936);   // W_enc^T 512x512 bf16
  unsigned short* WDT = (unsigned short*)(ws + 13108224);   // W_dec^T 512x512 bf16
  unsigned short* WGT = (unsigned short*)(ws + 13632512);   // W_gen^T 80x512 bf16
  int* TOK            = (int*)(ws + 13714432);              // 16x3072 int
  float* MELT         = (float*)(ws + 13911040);            // 80x4104 f32
  int* BAR            = (int*)(ws + 15224320);              // 4 barrier counters

  float* out = (float*)d_out;
  float* durout = out + (size_t)B_ * MELS_ * T_;            // 3,932,160

  hipMemsetAsync(BAR, 0, 16, stream);                       // zero barrier counters
  fused_all<<<NBLK, 256, 0, stream>>>(src, dur, emb, pos, Wenc, benc, Wdur, bdur,
                                      Wdec, bdec, Wgen, bgen,
                                      X, ENC, DEC, WET, WDT, WGT, TOK, MELT, BAR,
                                      out, durout);
}

// Round 4
// 145.141 us; speedup vs baseline: 2.1057x; 2.1057x over previous
//
#include <hip/hip_runtime.h>

#define D_ 512
#define L_ 256
#define B_ 16
#define T_ 3072
#define MELS_ 80
#define R_ 4096          // B_*L_ unique token rows
#define CS_ 4104         // mel^T column stride (floats)

typedef __bf16 bf16x8 __attribute__((ext_vector_type(8)));
typedef float f32x4 __attribute__((ext_vector_type(4)));

__device__ __forceinline__ unsigned f2bf(float f) {
  union { float f; unsigned u; } x; x.f = f;
  return (x.u + 0x7FFFu + ((x.u >> 16) & 1u)) >> 16;   // RNE
}
__device__ __forceinline__ float bf2f(unsigned h) {
  union { unsigned u; float f; } x; x.u = h << 16;
  return x.f;
}

// dst[n][k] = bf16(src[k][n]) ; src is [512][N] f32, dst is [N][512] bf16
__device__ __forceinline__ void transw_dev(const float* __restrict__ src,
                                           unsigned short* __restrict__ dst,
                                           int N, int local, float* sh) {
  int kt = local & 7, nt = local >> 3;
  int k0 = kt * 64, n0 = nt * 64;
  int tid = threadIdx.x;
  int c = tid & 63, r4 = tid >> 6;
  for (int it = 0; it < 16; ++it) {
    int r = it * 4 + r4;
    int n = n0 + c;
    sh[r * 65 + c] = (n < N) ? src[(k0 + r) * N + n] : 0.f;
  }
  __syncthreads();
  for (int it = 0; it < 16; ++it) {
    int r = it * 4 + r4;
    int n = n0 + r;
    if (n < N) dst[n * D_ + k0 + c] = (unsigned short)f2bf(sh[c * 65 + r]);
  }
}

// cumsum(dur) + searchsorted(right) -> enc-row index per frame (R_ = invalid)
__device__ __forceinline__ void tok_dev(const int* __restrict__ dur,
                                        int* __restrict__ TOK, int b, int* cs) {
  int tid = threadIdx.x;
  cs[tid] = dur[b * L_ + tid];
  for (int off = 1; off < L_; off <<= 1) {
    __syncthreads();
    int v = (tid >= off) ? cs[tid - off] : 0;
    __syncthreads();
    cs[tid] += v;
  }
  __syncthreads();
  for (int t = tid; t < T_; t += 256) {
    int lo = 0, hi = L_;
    while (lo < hi) { int mid = (lo + hi) >> 1; if (cs[mid] <= t) lo = mid + 1; else hi = mid; }
    TOK[b * T_ + t] = (lo < L_) ? (b * L_ + lo) : R_;
  }
}

// ---- L1: weight transposes + token map + ENC zero row ----
__global__ void prep_lite(const int* __restrict__ dur,
                          const float* __restrict__ Wenc, const float* __restrict__ Wdec,
                          const float* __restrict__ Wgen,
                          unsigned short* __restrict__ ENC,
                          unsigned short* __restrict__ WET, unsigned short* __restrict__ WDT,
                          unsigned short* __restrict__ WGT, int* __restrict__ TOK) {
  __shared__ float sh[64 * 65];
  int bid = blockIdx.x, tid = threadIdx.x;
  if (bid < 64)       transw_dev(Wenc, WET, 512, bid, sh);
  else if (bid < 128) transw_dev(Wdec, WDT, 512, bid - 64, sh);
  else if (bid < 144) transw_dev(Wgen, WGT, MELS_, bid - 128, sh);
  else if (bid < 160) tok_dev(dur, TOK, bid - 144, (int*)sh);
  else {                                              // ENC[R_] = 0
    if (tid < 64) {
      uint4 z = {0u, 0u, 0u, 0u};
      *(uint4*)(ENC + (size_t)R_ * D_ + (tid & 63) * 8) = z;
    }
  }
}

// ---- L2: encoder GEMM. A-panel = bf16(emb[src]+pos) staged once to LDS; ----
// ---- per-kstep B from WET via global_load_lds. ENC = relu(A@WET^T + benc) ----
__global__ __launch_bounds__(256, 2) void gemm_enc(
    const int* __restrict__ src, const float* __restrict__ emb,
    const float* __restrict__ pos, const unsigned short* __restrict__ WET,
    const float* __restrict__ benc, unsigned short* __restrict__ ENC) {
  __shared__ short lsA[64 * 512];                     // 64 KB full A-panel
  __shared__ short lsB[64 * 64];                      // 8 KB per-kstep B
  int tid = threadIdx.x;
  int lane = tid & 63, w = tid >> 6;
  int wm = w >> 1, wn = w & 1;
  int col = lane & 15, quad = lane >> 4;
  int m0 = (blockIdx.x >> 3) * 64, n0 = (blockIdx.x & 7) * 64;

  // --- stage A panel: row = tid>>2 (64 rows), q = tid&3 covers k q*128..+127 ---
  {
    int row = tid >> 2, q = tid & 3;
    int grow = m0 + row;
    const float* ep = emb + (size_t)src[grow] * D_;
    const float* pp = pos + (size_t)(grow & (L_ - 1)) * D_;
    for (int j = 0; j < 16; ++j) {
      int k = q * 128 + j * 8;
      float4 a0 = *(const float4*)(ep + k), a1 = *(const float4*)(ep + k + 4);
      float4 b0 = *(const float4*)(pp + k), b1 = *(const float4*)(pp + k + 4);
      uint4 o;
      o.x = f2bf(a0.x + b0.x) | (f2bf(a0.y + b0.y) << 16);
      o.y = f2bf(a0.z + b0.z) | (f2bf(a0.w + b0.w) << 16);
      o.z = f2bf(a1.x + b1.x) | (f2bf(a1.y + b1.y) << 16);
      o.w = f2bf(a1.z + b1.z) | (f2bf(a1.w + b1.w) << 16);
      int slot = ((k >> 3) + row) & 63;               // sg stored at slot (sg+row)&63
      *(uint4*)(lsA + (size_t)row * 512 + slot * 8) = o;
    }
  }
  __syncthreads();

  f32x4 acc[2][2] = {};
  for (int ks = 0; ks < 8; ++ks) {
    __syncthreads();                                  // lsB reuse guard
    for (int it = 0; it < 2; ++it) {
      int linear = it * 256 + tid;
      int brow = linear >> 3, p = linear & 7;
      int seg = (p + brow) & 7;
      const unsigned short* gb = WET + (size_t)(n0 + brow) * D_ + ks * 64 + seg * 8;
      short* lb = lsB + (size_t)(it * 256 + (tid & ~63)) * 8;
      __builtin_amdgcn_global_load_lds((const __attribute__((address_space(1))) void*)gb,
                                       (__attribute__((address_space(3))) void*)lb, 16, 0, 0);
    }
    __syncthreads();                                  // drains vmcnt(0)
    for (int kk = 0; kk < 2; ++kk) {
      int sl = kk * 4 + quad;                         // B chunk 0..7
      int sg = ks * 8 + sl;                           // A chunk 0..63
      bf16x8 af[2], bfr[2];
      for (int mt = 0; mt < 2; ++mt) {
        int r = wm * 32 + mt * 16 + col;
        af[mt] = *(const bf16x8*)(lsA + (size_t)r * 512 + ((sg + r) & 63) * 8);
      }
      for (int nt = 0; nt < 2; ++nt) {
        int r = wn * 32 + nt * 16 + col;
        bfr[nt] = *(const bf16x8*)(lsB + (size_t)r * 64 + ((sl - r) & 7) * 8);
      }
      for (int mt = 0; mt < 2; ++mt)
        for (int nt = 0; nt < 2; ++nt)
          acc[mt][nt] = __builtin_amdgcn_mfma_f32_16x16x32_bf16(af[mt], bfr[nt], acc[mt][nt], 0, 0, 0);
    }
  }
  for (int nt = 0; nt < 2; ++nt) {
    int n = n0 + wn * 32 + nt * 16 + col;
    float bn = benc[n];
    for (int mt = 0; mt < 2; ++mt) {
      int mb = m0 + wm * 32 + mt * 16 + quad * 4;
      for (int i = 0; i < 4; ++i) {
        float v = acc[mt][nt][i] + bn;
        v = v > 0.f ? v : 0.f;
        ENC[(size_t)(mb + i) * D_ + n] = (unsigned short)f2bf(v);
      }
    }
  }
}

// ---- L3: decoder GEMM (A = ENC panel via global_load_lds upfront; B = WDT) ----
// ---- + dur-head tail blocks (bid >= 520): durout[row] = ENC[row]·wdur + bdur ----
__global__ __launch_bounds__(256, 2) void gemm_dec(
    const unsigned short* __restrict__ ENC, const unsigned short* __restrict__ WDT,
    const float* __restrict__ bdec, unsigned short* __restrict__ DEC,
    const float* __restrict__ wdur, const float* __restrict__ bdur,
    float* __restrict__ durout) {
  __shared__ short lsA[64 * 512];
  __shared__ short lsB[64 * 64];
  int bid = blockIdx.x, tid = threadIdx.x;
  int lane = tid & 63, w = tid >> 6;

  if (bid >= 520) {                                   // duration head: 4 rows/wave
    int b2 = bid - 520;
    float4 w0 = *(const float4*)(wdur + lane * 8);
    float4 w1 = *(const float4*)(wdur + lane * 8 + 4);
    float bv = bdur[0];
    for (int rep = 0; rep < 4; ++rep) {
      int row = b2 * 16 + w * 4 + rep;
      const uint4 e = *(const uint4*)(ENC + (size_t)row * D_ + lane * 8);
      float s = 0.f;
      s += bf2f(e.x & 0xffffu) * w0.x;  s += bf2f(e.x >> 16) * w0.y;
      s += bf2f(e.y & 0xffffu) * w0.z;  s += bf2f(e.y >> 16) * w0.w;
      s += bf2f(e.z & 0xffffu) * w1.x;  s += bf2f(e.z >> 16) * w1.y;
      s += bf2f(e.w & 0xffffu) * w1.z;  s += bf2f(e.w >> 16) * w1.w;
      for (int off = 32; off > 0; off >>= 1) s += __shfl_down(s, off, 64);
      if (lane == 0) durout[row] = s + bv;
    }
    return;
  }

  int wm = w >> 1, wn = w & 1;
  int col = lane & 15, quad = lane >> 4;
  int m0 = (bid >> 3) * 64, n0 = (bid & 7) * 64;

  // --- stage full A panel via async 16B loads; LDS[row][p] = seg (p+row)&63 ---
  for (int it = 0; it < 16; ++it) {
    int linear = it * 256 + tid;
    int arow = linear >> 6, p = linear & 63;          // p == lane
    int seg = (p + arow) & 63;
    const unsigned short* ga = ENC + (size_t)min(m0 + arow, R_) * D_ + seg * 8;
    short* la = lsA + (size_t)(it * 256 + (tid & ~63)) * 8;
    __builtin_amdgcn_global_load_lds((const __attribute__((address_space(1))) void*)ga,
                                     (__attribute__((address_space(3))) void*)la, 16, 0, 0);
  }

  f32x4 acc[2][2] = {};
  for (int ks = 0; ks < 8; ++ks) {
    if (ks) __syncthreads();                          // lsB reuse guard
    for (int it = 0; it < 2; ++it) {
      int linear = it * 256 + tid;
      int brow = linear >> 3, p = linear & 7;
      int seg = (p + brow) & 7;
      const unsigned short* gb = WDT + (size_t)(n0 + brow) * D_ + ks * 64 + seg * 8;
      short* lb = lsB + (size_t)(it * 256 + (tid & ~63)) * 8;
      __builtin_amdgcn_global_load_lds((const __attribute__((address_space(1))) void*)gb,
                                       (__attribute__((address_space(3))) void*)lb, 16, 0, 0);
    }
    __syncthreads();                                  // drains vmcnt(0): A panel + B tile
    for (int kk = 0; kk < 2; ++kk) {
      int sl = kk * 4 + quad;
      int sg = ks * 8 + sl;
      bf16x8 af[2], bfr[2];
      for (int mt = 0; mt < 2; ++mt) {
        int r = wm * 32 + mt * 16 + col;
        af[mt] = *(const bf16x8*)(lsA + (size_t)r * 512 + ((sg - r) & 63) * 8);
      }
      for (int nt = 0; nt < 2; ++nt) {
        int r = wn * 32 + nt * 16 + col;
        bfr[nt] = *(const bf16x8*)(lsB + (size_t)r * 64 + ((sl - r) & 7) * 8);
      }
      for (int mt = 0; mt < 2; ++mt)
        for (int nt = 0; nt < 2; ++nt)
          acc[mt][nt] = __builtin_amdgcn_mfma_f32_16x16x32_bf16(af[mt], bfr[nt], acc[mt][nt], 0, 0, 0);
    }
  }
  for (int nt = 0; nt < 2; ++nt) {
    int n = n0 + wn * 32 + nt * 16 + col;
    float bn = bdec[n];
    for (int mt = 0; mt < 2; ++mt) {
      int mb = m0 + wm * 32 + mt * 16 + quad * 4;
      for (int i = 0; i < 4; ++i) {
        int m = mb + i;
        if (m < R_ + 1) {
          float v = acc[mt][nt][i] + bn;
          v = v > 0.f ? v : 0.f;
          DEC[(size_t)m * D_ + n] = (unsigned short)f2bf(v);
        }
      }
    }
  }
}

// ---- L4: mel^T[m][r] = dec[r]·W_gen[:,m] + b_gen[m] ; K split over 4 waves ----
__global__ void genk(const unsigned short* __restrict__ dec, const unsigned short* __restrict__ wgT,
                     const float* __restrict__ bgen, float* __restrict__ melT) {
  __shared__ float sh[4 * 80 * 16];
  int tid = threadIdx.x;
  int lane = tid & 63, w = tid >> 6;
  int col = lane & 15, quad = lane >> 4;
  int n0 = blockIdx.x * 16;
  int n = n0 + col;
  int nc = min(n, R_);
  f32x4 acc[5] = {};
  const unsigned short* dp = dec + (size_t)nc * D_ + quad * 8;
  for (int ks = 0; ks < 4; ++ks) {
    int k0 = (w * 4 + ks) * 32;
    bf16x8 bfr = *(const bf16x8*)(dp + k0);
    for (int mt = 0; mt < 5; ++mt) {
      bf16x8 afr = *(const bf16x8*)(wgT + (size_t)(mt * 16 + col) * D_ + k0 + quad * 8);
      acc[mt] = __builtin_amdgcn_mfma_f32_16x16x32_bf16(afr, bfr, acc[mt], 0, 0, 0);
    }
  }
  for (int mt = 0; mt < 5; ++mt)
    for (int i = 0; i < 4; ++i)
      sh[w * 1280 + (mt * 16 + quad * 4 + i) * 16 + col] = acc[mt][i];
  __syncthreads();
  for (int j = 0; j < 5; ++j) {
    int idx = j * 256 + tid;
    float v = sh[idx] + sh[1280 + idx] + sh[2560 + idx] + sh[3840 + idx];
    int m = idx >> 4;
    int nn = n0 + (idx & 15);
    if (nn <= R_) melT[(size_t)m * CS_ + nn] = v + bgen[m];
  }
}

// ---- L5: out[b][m][t] = mel^T[m][tok[b][t]] ; float4 coalesced stores ----
__global__ void outk(const int* __restrict__ TOK, const float* __restrict__ melT,
                     float* __restrict__ out) {
  int b = blockIdx.y;
  int tl = blockIdx.x * 128 + (threadIdx.x & 31) * 4;
  int m0 = threadIdx.x >> 5;
  int4 tg = *(const int4*)(TOK + b * T_ + tl);
  float* ob = out + (size_t)b * MELS_ * T_ + tl;
  for (int it = 0; it < 10; ++it) {
    int m = m0 + it * 8;
    const float* mr = melT + (size_t)m * CS_;
    float4 v = make_float4(mr[tg.x], mr[tg.y], mr[tg.z], mr[tg.w]);
    *(float4*)(ob + (size_t)m * T_) = v;
  }
}

extern "C" void kernel_launch(void* const* d_in, const int* in_sizes, int n_in,
                              void* d_out, int out_size, void* d_ws, size_t ws_size,
                              hipStream_t stream) {
  const int* src = (const int*)d_in[0];
  const int* dur = (const int*)d_in[1];
  const float* emb = (const float*)d_in[3];
  const float* pos = (const float*)d_in[4];
  const float* Wenc = (const float*)d_in[5];
  const float* benc = (const float*)d_in[6];
  const float* Wdur = (const float*)d_in[7];
  const float* bdur = (const float*)d_in[8];
  const float* Wdec = (const float*)d_in[9];
  const float* bdec = (const float*)d_in[10];
  const float* Wgen = (const float*)d_in[11];
  const float* bgen = (const float*)d_in[12];

  char* ws = (char*)d_ws;
  unsigned short* ENC = (unsigned short*)(ws + 0);          // 4097x512 bf16 (row 4096 = 0)
  unsigned short* DEC = (unsigned short*)(ws + 4195328);    // 4097x512 bf16
  unsigned short* WET = (unsigned short*)(ws + 8390656);    // W_enc^T 512x512 bf16
  unsigned short* WDT = (unsigned short*)(ws + 8914944);    // W_dec^T 512x512 bf16
  unsigned short* WGT = (unsigned short*)(ws + 9439232);    // W_gen^T 80x512 bf16
  int* TOK            = (int*)(ws + 9521152);               // 16x3072 int
  float* MELT         = (float*)(ws + 9717760);             // 80x4104 f32

  float* out = (float*)d_out;
  float* durout = out + (size_t)B_ * MELS_ * T_;            // 3,932,160

  prep_lite<<<161, 256, 0, stream>>>(dur, Wenc, Wdec, Wgen, ENC, WET, WDT, WGT, TOK);
  gemm_enc<<<512, 256, 0, stream>>>(src, emb, pos, WET, benc, ENC);
  gemm_dec<<<776, 256, 0, stream>>>(ENC, WDT, bdec, DEC, Wdur, bdur, durout);
  genk<<<257, 256, 0, stream>>>(DEC, WGT, bgen, MELT);
  outk<<<dim3(24, 16), 256, 0, stream>>>(TOK, MELT, out);
}